// Round 1
// baseline (549.815 us; speedup 1.0000x reference)
//
#include <hip/hip_runtime.h>
#include <hip/hip_bf16.h>

// ---------------------------------------------------------------------------
// Attention_32100585571137 : full pipeline
//   qkv = x @ w_qkv^T                (3072x768 @ 768x2304)
//   idkv = id_total @ w_idkv^T + b   (1024x768 @ 768x780)
//   k_m_mod = k_m * (1+tanh(id_k));  v_m_mod = v_m + id_v
//   attn_m = top50-softmax(q_m k_m_mod^T) @ v_m_mod      (L=1024, k=512)
//   attn_s = top50-softmax(q_s [mem_k;k]^T) @ [mem_v;v'] (L=5120, k=2560)
//   out = concat @ w_proj^T + b_proj
// outputs (f32, concat): out(3072*768), k_m_mod(12*1024*64), v_m_mod(12*1024*64)
// ---------------------------------------------------------------------------

typedef __bf16 bf16;
typedef __attribute__((ext_vector_type(8))) __bf16 bf16x8;
typedef __attribute__((ext_vector_type(4))) __bf16 bf16x4;
typedef __attribute__((ext_vector_type(4))) float f32x4;

#define AS1 __attribute__((address_space(1)))
#define AS3 __attribute__((address_space(3)))

__device__ __forceinline__ void gll16(const void* g, void* l) {
  __builtin_amdgcn_global_load_lds((const AS1 void*)g, (AS3 void*)l, 16, 0, 0);
}

// ------------------------- f32 -> bf16 convert (x4) ------------------------
__global__ void to_bf16_k(const float4* __restrict__ s, bf16x4* __restrict__ d, int n4) {
  int i = blockIdx.x * 256 + threadIdx.x;
  if (i < n4) {
    float4 f = s[i];
    bf16x4 o;
    o[0] = (bf16)f.x; o[1] = (bf16)f.y; o[2] = (bf16)f.z; o[3] = (bf16)f.w;
    d[i] = o;
  }
}

// ------------------------- NT GEMM: C = A * B^T ----------------------------
// A: M x K bf16 (lda), B: N x K bf16 (ldb), C: M x N (ldc) f32 or bf16
// M % BM == 0, K % 32 == 0 required. N ragged allowed iff NCLAMP.
template<int BM, int BN, int WM, int WN, bool CBF16, bool NCLAMP>
__global__ __launch_bounds__(256, 2)
void gemm_nt(const bf16* __restrict__ A, const bf16* __restrict__ B,
             void* __restrict__ Cp, const float* __restrict__ bias,
             int M, int N, int K, int lda, int ldb, int ldc,
             long sA, long sB, long sC)
{
  constexpr int BK = 32;
  constexpr int MF = WM / 16, NF = WN / 16;
  constexpr int NWN = BN / WN;
  __shared__ __align__(16) bf16 As[BM * BK];
  __shared__ __align__(16) bf16 Bs[BN * BK];
  const int tid  = threadIdx.x;
  const int lane = tid & 63;
  const int wid  = tid >> 6;
  const int wm = (wid / NWN) * WM;
  const int wn = (wid % NWN) * WN;
  const int m0 = blockIdx.y * BM;
  const int n0 = blockIdx.x * BN;
  const bf16* Ab = A + (long)blockIdx.z * sA;
  const bf16* Bb = B + (long)blockIdx.z * sB;

  f32x4 acc[MF][NF] = {};
  const int wbase = wid << 10;      // wave-uniform LDS byte base within a 4KB pass
  const int aoffb = tid * 16;       // this thread's byte slot

  for (int k0 = 0; k0 < K; k0 += BK) {
    #pragma unroll
    for (int i = 0; i < (BM * BK * 2) / 4096; ++i) {
      int off = i * 4096 + aoffb;
      int row = off >> 6, cb = off & 63;       // 64 B per 32-elem row
      const bf16* g = Ab + (long)(m0 + row) * lda + (k0 + (cb >> 1));
      gll16(g, (char*)As + i * 4096 + wbase);
    }
    #pragma unroll
    for (int i = 0; i < (BN * BK * 2) / 4096; ++i) {
      int off = i * 4096 + aoffb;
      int row = off >> 6, cb = off & 63;
      int rn = n0 + row;
      if (NCLAMP) rn = (rn < N) ? rn : (N - 1);
      const bf16* g = Bb + (long)rn * ldb + (k0 + (cb >> 1));
      gll16(g, (char*)Bs + i * 4096 + wbase);
    }
    __syncthreads();
    bf16x8 af[MF], bfr[NF];
    #pragma unroll
    for (int i = 0; i < MF; ++i)
      af[i] = *reinterpret_cast<const bf16x8*>(&As[(wm + i * 16 + (lane & 15)) * BK + ((lane >> 4) * 8)]);
    #pragma unroll
    for (int j = 0; j < NF; ++j)
      bfr[j] = *reinterpret_cast<const bf16x8*>(&Bs[(wn + j * 16 + (lane & 15)) * BK + ((lane >> 4) * 8)]);
    #pragma unroll
    for (int i = 0; i < MF; ++i)
      #pragma unroll
      for (int j = 0; j < NF; ++j)
        acc[i][j] = __builtin_amdgcn_mfma_f32_16x16x32_bf16(af[i], bfr[j], acc[i][j], 0, 0, 0);
    __syncthreads();
  }

  const long cbase = (long)blockIdx.z * sC;
  #pragma unroll
  for (int i = 0; i < MF; ++i) {
    const int r0 = m0 + wm + i * 16 + ((lane >> 4) << 2);
    #pragma unroll
    for (int j = 0; j < NF; ++j) {
      const int c = n0 + wn + j * 16 + (lane & 15);
      if (NCLAMP && c >= N) continue;
      const float bv = bias ? bias[c] : 0.0f;
      #pragma unroll
      for (int r = 0; r < 4; ++r) {
        float v = acc[i][j][r] + bv;
        long idx = cbase + (long)(r0 + r) * ldc + c;
        if (CBF16) ((bf16*)Cp)[idx] = (bf16)v;
        else       ((float*)Cp)[idx] = v;
      }
    }
  }
}

// --------------- split qkv -> q(scaled), k_full, k_m_mod -------------------
__global__ void split_qk_k(const float* __restrict__ qkv, const float* __restrict__ idkv,
                           const float* __restrict__ mem_k,
                           bf16* __restrict__ q_bf, bf16* __restrict__ kfull,
                           bf16* __restrict__ kmm, float* __restrict__ out_kmm)
{
  int idx = blockIdx.x * 256 + threadIdx.x;      // over 12*5120*64
  if (idx >= 12 * 5120 * 64) return;
  int d  = idx & 63;
  int hj = idx >> 6;
  int h  = hj / 5120;
  int j  = hj - h * 5120;
  if (j < 2048) {
    kfull[idx] = (bf16)mem_k[((h * 2048 + j) << 6) + d];
  } else {
    int n = j - 2048;
    int base = n * 2304 + (h << 6) + d;
    float qv = qkv[base];
    float kv = qkv[base + 768];
    q_bf[((h * 3072 + n) << 6) + d] = (bf16)(qv * 0.125f);
    kfull[idx] = (bf16)kv;
    if (n < 1024) {
      float m  = 1.0f + tanhf(idkv[n * 780 + h]);
      float km = kv * m;
      int o = ((h * 1024 + n) << 6) + d;
      kmm[o]     = (bf16)km;
      out_kmm[o] = km;
    }
  }
}

// --------------- build v^T (64 x 5120 per head) + v_m_mod outputs ----------
__global__ void build_vT_k(const float* __restrict__ qkv, const float* __restrict__ idkv,
                           const float* __restrict__ mem_v,
                           bf16* __restrict__ vT, float* __restrict__ out_vm)
{
  __shared__ float tile[64][65];
  int h  = blockIdx.y;
  int j0 = blockIdx.x << 6;
  int tid = threadIdx.x;
  #pragma unroll
  for (int i = 0; i < 16; ++i) {
    int el = i * 256 + tid;
    int jj = el >> 6, d = el & 63;
    int j = j0 + jj;
    float v;
    if (j < 2048) {
      v = mem_v[((h * 2048 + j) << 6) + d];
    } else {
      int n = j - 2048;
      v = qkv[n * 2304 + 1536 + (h << 6) + d];
      if (n < 1024) {
        v += idkv[n * 780 + 12 + (h << 6) + d];
        out_vm[((h * 1024 + n) << 6) + d] = v;
      }
    }
    tile[jj][d] = v;
  }
  __syncthreads();
  #pragma unroll
  for (int i = 0; i < 16; ++i) {
    int el = i * 256 + tid;
    int d = el >> 6, jj = el & 63;
    vT[((long)(h * 64 + d)) * 5120 + j0 + jj] = (bf16)tile[jj][d];
  }
}

// --------------- top-(L/2) softmax, in-place on bf16 rows ------------------
// one 256-thread block per row. Histogram-threshold selection (approximate at
// the boundary bin by <= ~10 elements of ~2560 — far inside tolerance).
template<int L>
__global__ __launch_bounds__(256) void topk_softmax(bf16* __restrict__ S)
{
  constexpr int K2 = L / 2;
  constexpr int NB = 2048;
  __shared__ float vals[L];
  __shared__ int   hist[NB];
  __shared__ int   ps[256];
  __shared__ float smax4[4], smin4[4], ssum4[4];
  __shared__ float tsh;

  bf16* __restrict__ row = S + (long)blockIdx.x * L;
  const int tid  = threadIdx.x;
  const int lane = tid & 63;
  const int wv   = tid >> 6;

  float vmax = -3.0e38f, vmin = 3.0e38f;
  for (int s = tid; s < L / 8; s += 256) {
    bf16x8 v8 = *reinterpret_cast<const bf16x8*>(row + s * 8);
    #pragma unroll
    for (int e = 0; e < 8; ++e) {
      float f = (float)v8[e];
      vals[s * 8 + e] = f;
      vmax = fmaxf(vmax, f);
      vmin = fminf(vmin, f);
    }
  }
  for (int b = tid; b < NB; b += 256) hist[b] = 0;
  #pragma unroll
  for (int off = 32; off; off >>= 1) {
    vmax = fmaxf(vmax, __shfl_down(vmax, off, 64));
    vmin = fminf(vmin, __shfl_down(vmin, off, 64));
  }
  if (lane == 0) { smax4[wv] = vmax; smin4[wv] = vmin; }
  __syncthreads();
  vmax = fmaxf(fmaxf(smax4[0], smax4[1]), fmaxf(smax4[2], smax4[3]));
  vmin = fminf(fminf(smin4[0], smin4[1]), fminf(smin4[2], smin4[3]));
  float span = vmax - vmin;
  float sc = (span > 0.0f) ? (float)NB / span * 0.999999f : 0.0f;

  for (int s = tid; s < L; s += 256) {
    int b = (int)((vals[s] - vmin) * sc);
    b = (b > NB - 1) ? NB - 1 : b;
    atomicAdd(&hist[b], 1);
  }
  __syncthreads();

  int csum = 0;
  #pragma unroll
  for (int e = 0; e < 8; ++e) csum += hist[tid * 8 + e];
  ps[tid] = csum;
  __syncthreads();
  for (int off = 1; off < 256; off <<= 1) {           // suffix scan
    int add = (tid + off < 256) ? ps[tid + off] : 0;
    __syncthreads();
    ps[tid] += add;
    __syncthreads();
  }
  int above = (tid < 255) ? ps[tid + 1] : 0;
  if (ps[tid] >= K2 && above < K2) {                  // unique thread
    int cum = above;
    int b = tid * 8 + 7;
    while (b > tid * 8) {
      if (cum + hist[b] >= K2) break;
      cum += hist[b];
      --b;
    }
    tsh = (sc > 0.0f) ? (vmin + (float)b / sc) : vmin;
  }
  __syncthreads();
  const float t = tsh;

  float lsum = 0.0f;
  for (int s = tid; s < L; s += 256) {
    float v = vals[s];
    float e = (v >= t) ? __expf(v - vmax) : 0.0f;
    vals[s] = e;
    lsum += e;
  }
  #pragma unroll
  for (int off = 32; off; off >>= 1) lsum += __shfl_down(lsum, off, 64);
  if (lane == 0) ssum4[wv] = lsum;
  __syncthreads();
  const float inv = 1.0f / (ssum4[0] + ssum4[1] + ssum4[2] + ssum4[3]);
  for (int s = tid; s < L / 8; s += 256) {
    bf16x8 o;
    #pragma unroll
    for (int e = 0; e < 8; ++e) o[e] = (bf16)(vals[s * 8 + e] * inv);
    *reinterpret_cast<bf16x8*>(row + s * 8) = o;
  }
}

// ---------------------------------------------------------------------------
extern "C" void kernel_launch(void* const* d_in, const int* in_sizes, int n_in,
                              void* d_out, int out_size, void* d_ws, size_t ws_size,
                              hipStream_t stream)
{
  (void)in_sizes; (void)n_in; (void)out_size;
  const float* x      = (const float*)d_in[0];
  const float* id_tot = (const float*)d_in[1];
  const float* mem_k  = (const float*)d_in[2];
  const float* mem_v  = (const float*)d_in[3];
  const float* w_qkv  = (const float*)d_in[4];
  const float* w_idkv = (const float*)d_in[5];
  const float* b_idkv = (const float*)d_in[6];
  const float* w_proj = (const float*)d_in[7];
  const float* b_proj = (const float*)d_in[8];

  float* out     = (float*)d_out;                    // 3072*768
  float* out_kmm = out + (size_t)3072 * 768;         // 12*1024*64
  float* out_vm  = out_kmm + (size_t)12 * 1024 * 64; // 12*1024*64

  char* w = (char*)d_ws;
  auto alloc = [&](size_t b) { char* p = w; w += (b + 255) & ~(size_t)255; return p; };
  bf16*  x_bf     = (bf16*) alloc((size_t)3072 * 768 * 2);
  bf16*  wqkv_bf  = (bf16*) alloc((size_t)2304 * 768 * 2);
  bf16*  id_bf    = (bf16*) alloc((size_t)1024 * 768 * 2);
  bf16*  widkv_bf = (bf16*) alloc((size_t)780 * 768 * 2);
  bf16*  wproj_bf = (bf16*) alloc((size_t)768 * 768 * 2);
  float* qkv_f    = (float*)alloc((size_t)3072 * 2304 * 4);
  float* idkv_f   = (float*)alloc((size_t)1024 * 780 * 4);
  bf16*  q_bf     = (bf16*) alloc((size_t)12 * 3072 * 64 * 2);
  bf16*  kfull_bf = (bf16*) alloc((size_t)12 * 5120 * 64 * 2);
  bf16*  vT_bf    = (bf16*) alloc((size_t)12 * 64 * 5120 * 2);
  bf16*  kmm_bf   = (bf16*) alloc((size_t)12 * 1024 * 64 * 2);
  bf16*  S_m      = (bf16*) alloc((size_t)12 * 1024 * 1024 * 2);
  float* av_f     = (float*)alloc((size_t)3072 * 768 * 4);
  bf16*  xatt_bf  = (bf16*) alloc((size_t)3072 * 768 * 2);
  size_t fixed = (size_t)(w - (char*)d_ws);

  int CH = 1;
  const int chs[6] = {12, 6, 4, 3, 2, 1};
  for (int i = 0; i < 6; ++i) {
    if (fixed + (size_t)chs[i] * 2048 * 5120 * 2 + 256 <= ws_size) { CH = chs[i]; break; }
  }
  if (fixed + (size_t)CH * 2048 * 5120 * 2 + 256 > ws_size) return;  // ws too small: fail loudly
  bf16* S_s = (bf16*)alloc((size_t)CH * 2048 * 5120 * 2);

  // --- bf16 conversions ---
  to_bf16_k<<<2304, 256, 0, stream>>>((const float4*)x,      (bf16x4*)x_bf,     589824);
  to_bf16_k<<<1728, 256, 0, stream>>>((const float4*)w_qkv,  (bf16x4*)wqkv_bf,  442368);
  to_bf16_k<<< 768, 256, 0, stream>>>((const float4*)id_tot, (bf16x4*)id_bf,    196608);
  to_bf16_k<<< 585, 256, 0, stream>>>((const float4*)w_idkv, (bf16x4*)widkv_bf, 149760);
  to_bf16_k<<< 576, 256, 0, stream>>>((const float4*)w_proj, (bf16x4*)wproj_bf, 147456);

  // --- projections ---
  gemm_nt<128,128,64,64,false,false><<<dim3(18, 24, 1), 256, 0, stream>>>(
      x_bf, wqkv_bf, qkv_f, nullptr, 3072, 2304, 768, 768, 768, 2304, 0, 0, 0);
  gemm_nt<128,128,64,64,false,true><<<dim3(7, 8, 1), 256, 0, stream>>>(
      id_bf, widkv_bf, idkv_f, b_idkv, 1024, 780, 768, 768, 768, 780, 0, 0, 0);

  // --- split + modulate + transposes ---
  split_qk_k<<<15360, 256, 0, stream>>>(qkv_f, idkv_f, mem_k, q_bf, kfull_bf, kmm_bf, out_kmm);
  build_vT_k<<<dim3(80, 12, 1), 256, 0, stream>>>(qkv_f, idkv_f, mem_v, vT_bf, out_vm);

  // --- memory-branch attention (L=1024) ---
  gemm_nt<128,128,64,64,true,false><<<dim3(8, 8, 12), 256, 0, stream>>>(
      q_bf, kmm_bf, S_m, nullptr, 1024, 1024, 64, 64, 64, 1024,
      (long)3072 * 64, (long)1024 * 64, (long)1024 * 1024);
  topk_softmax<1024><<<12288, 256, 0, stream>>>(S_m);
  gemm_nt<128,64,64,32,false,false><<<dim3(1, 8, 12), 256, 0, stream>>>(
      S_m, vT_bf + 2048, av_f, nullptr, 1024, 64, 1024, 1024, 5120, 768,
      (long)1024 * 1024, (long)64 * 5120, 64);

  // --- streaming-branch attention (L=5120), chunked over heads ---
  for (int h0 = 0; h0 < 12; h0 += CH) {
    gemm_nt<128,128,64,64,true,false><<<dim3(40, 16, CH), 256, 0, stream>>>(
        q_bf + (size_t)h0 * 3072 * 64 + 1024 * 64, kfull_bf + (size_t)h0 * 5120 * 64,
        S_s, nullptr, 2048, 5120, 64, 64, 64, 5120,
        (long)3072 * 64, (long)5120 * 64, (long)2048 * 5120);
    topk_softmax<5120><<<CH * 2048, 256, 0, stream>>>(S_s);
    gemm_nt<128,64,64,32,false,false><<<dim3(1, 16, CH), 256, 0, stream>>>(
        S_s, vT_bf + (size_t)h0 * 64 * 5120, av_f + (size_t)1024 * 768 + h0 * 64,
        nullptr, 2048, 64, 5120, 5120, 5120, 768,
        (long)2048 * 5120, (long)64 * 5120, 64);
  }

  // --- output projection ---
  to_bf16_k<<<2304, 256, 0, stream>>>((const float4*)av_f, (bf16x4*)xatt_bf, 589824);
  gemm_nt<128,128,64,64,false,false><<<dim3(6, 24, 1), 256, 0, stream>>>(
      xatt_bf, wproj_bf, out, b_proj, 3072, 768, 768, 768, 768, 768, 0, 0, 0);
}

// Round 2
// 433.482 us; speedup vs baseline: 1.2684x; 1.2684x over previous
//
#include <hip/hip_runtime.h>
#include <hip/hip_bf16.h>

// ---------------------------------------------------------------------------
// Attention_32100585571137 : full pipeline (round 2)
//   - top-k softmax split into row_stats (t, max, 1/sum) + fused AV
//   - AV: split-K, A(raw S)->register softmax->bf16 frags, B(vT) via gll16
// ---------------------------------------------------------------------------

typedef __bf16 bf16;
typedef __attribute__((ext_vector_type(8))) __bf16 bf16x8;
typedef __attribute__((ext_vector_type(4))) __bf16 bf16x4;
typedef __attribute__((ext_vector_type(4))) float f32x4;

#define AS1 __attribute__((address_space(1)))
#define AS3 __attribute__((address_space(3)))

__device__ __forceinline__ void gll16(const void* g, void* l) {
  __builtin_amdgcn_global_load_lds((const AS1 void*)g, (AS3 void*)l, 16, 0, 0);
}

// ------------------------- f32 -> bf16 convert (x4) ------------------------
__global__ void to_bf16_k(const float4* __restrict__ s, bf16x4* __restrict__ d, int n4) {
  int i = blockIdx.x * 256 + threadIdx.x;
  if (i < n4) {
    float4 f = s[i];
    bf16x4 o;
    o[0] = (bf16)f.x; o[1] = (bf16)f.y; o[2] = (bf16)f.z; o[3] = (bf16)f.w;
    d[i] = o;
  }
}

// ------------------------- NT GEMM: C = A * B^T ----------------------------
template<int BM, int BN, int WM, int WN, bool CBF16, bool NCLAMP>
__global__ __launch_bounds__(256, 2)
void gemm_nt(const bf16* __restrict__ A, const bf16* __restrict__ B,
             void* __restrict__ Cp, const float* __restrict__ bias,
             int M, int N, int K, int lda, int ldb, int ldc,
             long sA, long sB, long sC)
{
  constexpr int BK = 32;
  constexpr int MF = WM / 16, NF = WN / 16;
  constexpr int NWN = BN / WN;
  __shared__ __align__(16) bf16 As[BM * BK];
  __shared__ __align__(16) bf16 Bs[BN * BK];
  const int tid  = threadIdx.x;
  const int lane = tid & 63;
  const int wid  = tid >> 6;
  const int wm = (wid / NWN) * WM;
  const int wn = (wid % NWN) * WN;
  const int m0 = blockIdx.y * BM;
  const int n0 = blockIdx.x * BN;
  const bf16* Ab = A + (long)blockIdx.z * sA;
  const bf16* Bb = B + (long)blockIdx.z * sB;

  f32x4 acc[MF][NF] = {};
  const int wbase = wid << 10;
  const int aoffb = tid * 16;

  for (int k0 = 0; k0 < K; k0 += BK) {
    #pragma unroll
    for (int i = 0; i < (BM * BK * 2) / 4096; ++i) {
      int off = i * 4096 + aoffb;
      int row = off >> 6, cb = off & 63;
      const bf16* g = Ab + (long)(m0 + row) * lda + (k0 + (cb >> 1));
      gll16(g, (char*)As + i * 4096 + wbase);
    }
    #pragma unroll
    for (int i = 0; i < (BN * BK * 2) / 4096; ++i) {
      int off = i * 4096 + aoffb;
      int row = off >> 6, cb = off & 63;
      int rn = n0 + row;
      if (NCLAMP) rn = (rn < N) ? rn : (N - 1);
      const bf16* g = Bb + (long)rn * ldb + (k0 + (cb >> 1));
      gll16(g, (char*)Bs + i * 4096 + wbase);
    }
    __syncthreads();
    bf16x8 af[MF], bfr[NF];
    #pragma unroll
    for (int i = 0; i < MF; ++i)
      af[i] = *reinterpret_cast<const bf16x8*>(&As[(wm + i * 16 + (lane & 15)) * BK + ((lane >> 4) * 8)]);
    #pragma unroll
    for (int j = 0; j < NF; ++j)
      bfr[j] = *reinterpret_cast<const bf16x8*>(&Bs[(wn + j * 16 + (lane & 15)) * BK + ((lane >> 4) * 8)]);
    #pragma unroll
    for (int i = 0; i < MF; ++i)
      #pragma unroll
      for (int j = 0; j < NF; ++j)
        acc[i][j] = __builtin_amdgcn_mfma_f32_16x16x32_bf16(af[i], bfr[j], acc[i][j], 0, 0, 0);
    __syncthreads();
  }

  const long cbase = (long)blockIdx.z * sC;
  #pragma unroll
  for (int i = 0; i < MF; ++i) {
    const int r0 = m0 + wm + i * 16 + ((lane >> 4) << 2);
    #pragma unroll
    for (int j = 0; j < NF; ++j) {
      const int c = n0 + wn + j * 16 + (lane & 15);
      if (NCLAMP && c >= N) continue;
      const float bv = bias ? bias[c] : 0.0f;
      #pragma unroll
      for (int r = 0; r < 4; ++r) {
        float v = acc[i][j][r] + bv;
        long idx = cbase + (long)(r0 + r) * ldc + c;
        if (CBF16) ((bf16*)Cp)[idx] = (bf16)v;
        else       ((float*)Cp)[idx] = v;
      }
    }
  }
}

// --------------- split qkv -> q(scaled), k_full, k_m_mod -------------------
__global__ void split_qk_k(const float* __restrict__ qkv, const float* __restrict__ idkv,
                           const float* __restrict__ mem_k,
                           bf16* __restrict__ q_bf, bf16* __restrict__ kfull,
                           bf16* __restrict__ kmm, float* __restrict__ out_kmm)
{
  int idx = blockIdx.x * 256 + threadIdx.x;
  if (idx >= 12 * 5120 * 64) return;
  int d  = idx & 63;
  int hj = idx >> 6;
  int h  = hj / 5120;
  int j  = hj - h * 5120;
  if (j < 2048) {
    kfull[idx] = (bf16)mem_k[((h * 2048 + j) << 6) + d];
  } else {
    int n = j - 2048;
    int base = n * 2304 + (h << 6) + d;
    float qv = qkv[base];
    float kv = qkv[base + 768];
    q_bf[((h * 3072 + n) << 6) + d] = (bf16)(qv * 0.125f);
    kfull[idx] = (bf16)kv;
    if (n < 1024) {
      float m  = 1.0f + tanhf(idkv[n * 780 + h]);
      float km = kv * m;
      int o = ((h * 1024 + n) << 6) + d;
      kmm[o]     = (bf16)km;
      out_kmm[o] = km;
    }
  }
}

// --------------- build v^T (64 x 5120 per head) + v_m_mod outputs ----------
__global__ void build_vT_k(const float* __restrict__ qkv, const float* __restrict__ idkv,
                           const float* __restrict__ mem_v,
                           bf16* __restrict__ vT, float* __restrict__ out_vm)
{
  __shared__ float tile[64][65];
  int h  = blockIdx.y;
  int j0 = blockIdx.x << 6;
  int tid = threadIdx.x;
  #pragma unroll
  for (int i = 0; i < 16; ++i) {
    int el = i * 256 + tid;
    int jj = el >> 6, d = el & 63;
    int j = j0 + jj;
    float v;
    if (j < 2048) {
      v = mem_v[((h * 2048 + j) << 6) + d];
    } else {
      int n = j - 2048;
      v = qkv[n * 2304 + 1536 + (h << 6) + d];
      if (n < 1024) {
        v += idkv[n * 780 + 12 + (h << 6) + d];
        out_vm[((h * 1024 + n) << 6) + d] = v;
      }
    }
    tile[jj][d] = v;
  }
  __syncthreads();
  #pragma unroll
  for (int i = 0; i < 16; ++i) {
    int el = i * 256 + tid;
    int d = el >> 6, jj = el & 63;
    vT[((long)(h * 64 + d)) * 5120 + j0 + jj] = (bf16)tile[jj][d];
  }
}

// --------------- row stats: threshold / max / 1-over-sum -------------------
// one 256-thread block per row; histogram threshold selection.
template<int L>
__global__ __launch_bounds__(256) void row_stats(const bf16* __restrict__ S,
                                                 float4* __restrict__ st)
{
  constexpr int K2 = L / 2;
  constexpr int NB = 2048;
  __shared__ float vals[L];
  __shared__ int   hist[NB];
  __shared__ int   ps[256];
  __shared__ float smax4[4], smin4[4], ssum4[4];
  __shared__ float tsh;

  const bf16* __restrict__ row = S + (long)blockIdx.x * L;
  const int tid  = threadIdx.x;
  const int lane = tid & 63;
  const int wv   = tid >> 6;

  float vmax = -3.0e38f, vmin = 3.0e38f;
  for (int s = tid; s < L / 8; s += 256) {
    bf16x8 v8 = *reinterpret_cast<const bf16x8*>(row + s * 8);
    #pragma unroll
    for (int e = 0; e < 8; ++e) {
      float f = (float)v8[e];
      vals[s * 8 + e] = f;
      vmax = fmaxf(vmax, f);
      vmin = fminf(vmin, f);
    }
  }
  for (int b = tid; b < NB; b += 256) hist[b] = 0;
  #pragma unroll
  for (int off = 32; off; off >>= 1) {
    vmax = fmaxf(vmax, __shfl_down(vmax, off, 64));
    vmin = fminf(vmin, __shfl_down(vmin, off, 64));
  }
  if (lane == 0) { smax4[wv] = vmax; smin4[wv] = vmin; }
  __syncthreads();
  vmax = fmaxf(fmaxf(smax4[0], smax4[1]), fmaxf(smax4[2], smax4[3]));
  vmin = fminf(fminf(smin4[0], smin4[1]), fminf(smin4[2], smin4[3]));
  float span = vmax - vmin;
  float sc = (span > 0.0f) ? (float)NB / span * 0.999999f : 0.0f;

  for (int s = tid; s < L; s += 256) {
    int b = (int)((vals[s] - vmin) * sc);
    b = (b > NB - 1) ? NB - 1 : b;
    atomicAdd(&hist[b], 1);
  }
  __syncthreads();

  int csum = 0;
  #pragma unroll
  for (int e = 0; e < 8; ++e) csum += hist[tid * 8 + e];
  ps[tid] = csum;
  __syncthreads();
  for (int off = 1; off < 256; off <<= 1) {
    int add = (tid + off < 256) ? ps[tid + off] : 0;
    __syncthreads();
    ps[tid] += add;
    __syncthreads();
  }
  int above = (tid < 255) ? ps[tid + 1] : 0;
  if (ps[tid] >= K2 && above < K2) {
    int cum = above;
    int b = tid * 8 + 7;
    while (b > tid * 8) {
      if (cum + hist[b] >= K2) break;
      cum += hist[b];
      --b;
    }
    tsh = (sc > 0.0f) ? (vmin + (float)b / sc) : vmin;
  }
  __syncthreads();
  const float t = tsh;

  float lsum = 0.0f;
  for (int s = tid; s < L; s += 256) {
    float v = vals[s];
    lsum += (v >= t) ? __expf(v - vmax) : 0.0f;
  }
  #pragma unroll
  for (int off = 32; off; off >>= 1) lsum += __shfl_down(lsum, off, 64);
  if (lane == 0) ssum4[wv] = lsum;
  __syncthreads();
  if (tid == 0) {
    float inv = 1.0f / (ssum4[0] + ssum4[1] + ssum4[2] + ssum4[3]);
    st[blockIdx.x] = make_float4(t, vmax, inv, 0.0f);
  }
}

// --------------- fused AV: P built in-register from raw S ------------------
// block = 64 rows x 64 cols, 4 waves (wave w: 16 rows). split-K over bz.
// S: [headLoc][Mrows][L] raw scores; stats indexed by global head.
template<int KSPLIT>
__global__ __launch_bounds__(256)
void av_fused(const bf16* __restrict__ S, const float4* __restrict__ st,
              const bf16* __restrict__ vT, float* __restrict__ part,
              int Mrows, int L, int vT_off, int outRowBase, int h0)
{
  __shared__ __align__(16) bf16 Bs[2][64 * 32];
  const int tid = threadIdx.x, lane = tid & 63, w = tid >> 6;
  const int hl = blockIdx.y;            // local head
  const int h  = h0 + hl;               // global head
  const int i0 = blockIdx.x * 64;
  const int kchunk = L / KSPLIT;
  const int kbase = blockIdx.z * kchunk;
  const int nsteps = kchunk / 32;

  const bf16* vTh = vT + (long)h * 64 * 5120 + vT_off;
  const int srow = tid >> 2, ssub = tid & 3;
  const bf16* bsrc = vTh + (long)srow * 5120 + kbase + ssub * 8;

  const int arow = i0 + w * 16 + (lane & 15);
  const bf16* ap = S + ((long)hl * Mrows + arow) * L + kbase + ((lane >> 4) * 8);
  const float4 s4 = st[h * Mrows + arow];
  const float t = s4.x, mx = s4.y;

  f32x4 acc[4] = {};
  gll16(bsrc, (char*)Bs[0] + tid * 16);
  __syncthreads();

  for (int s = 0; s < nsteps; ++s) {
    if (s + 1 < nsteps) gll16(bsrc + (s + 1) * 32, (char*)Bs[(s + 1) & 1] + tid * 16);
    bf16x8 a8 = *reinterpret_cast<const bf16x8*>(ap + s * 32);
    bf16x8 af;
    #pragma unroll
    for (int e = 0; e < 8; ++e) {
      float v = (float)a8[e];
      float ev = __expf(v - mx);
      af[e] = (bf16)((v >= t) ? ev : 0.0f);
    }
    const bf16* bb = Bs[s & 1];
    #pragma unroll
    for (int j = 0; j < 4; ++j) {
      bf16x8 b8 = *reinterpret_cast<const bf16x8*>(bb + (j * 16 + (lane & 15)) * 32 + ((lane >> 4) * 8));
      acc[j] = __builtin_amdgcn_mfma_f32_16x16x32_bf16(af, b8, acc[j], 0, 0, 0);
    }
    __syncthreads();
  }

  float* pp = part + (long)blockIdx.z * 3072 * 768;
  const int rb = i0 + w * 16 + ((lane >> 4) << 2);
  float inv4[4];
  #pragma unroll
  for (int r = 0; r < 4; ++r) inv4[r] = st[h * Mrows + rb + r].z;
  #pragma unroll
  for (int j = 0; j < 4; ++j) {
    const int c = h * 64 + j * 16 + (lane & 15);
    #pragma unroll
    for (int r = 0; r < 4; ++r)
      pp[(long)(outRowBase + rb + r) * 768 + c] = acc[j][r] * inv4[r];
  }
}

// --------------- reduce split-K partials + convert to bf16 -----------------
__global__ void reduce_cvt_k(const float4* __restrict__ part, bf16x4* __restrict__ xatt)
{
  const int idx = blockIdx.x * 256 + threadIdx.x;   // float4 over 3072*768
  if (idx >= 589824) return;
  const int row = idx / 192;                        // 768/4 per row
  constexpr long P4 = 589824;
  float4 a = part[idx];
  float4 b = part[idx + P4];
  float sx = a.x + b.x, sy = a.y + b.y, sz = a.z + b.z, sw = a.w + b.w;
  if (row >= 1024) {
    float4 c = part[idx + 2 * P4];
    float4 d = part[idx + 3 * P4];
    sx += c.x + d.x; sy += c.y + d.y; sz += c.z + d.z; sw += c.w + d.w;
  }
  bf16x4 o;
  o[0] = (bf16)sx; o[1] = (bf16)sy; o[2] = (bf16)sz; o[3] = (bf16)sw;
  xatt[idx] = o;
}

// ---------------------------------------------------------------------------
extern "C" void kernel_launch(void* const* d_in, const int* in_sizes, int n_in,
                              void* d_out, int out_size, void* d_ws, size_t ws_size,
                              hipStream_t stream)
{
  (void)in_sizes; (void)n_in; (void)out_size;
  const float* x      = (const float*)d_in[0];
  const float* id_tot = (const float*)d_in[1];
  const float* mem_k  = (const float*)d_in[2];
  const float* mem_v  = (const float*)d_in[3];
  const float* w_qkv  = (const float*)d_in[4];
  const float* w_idkv = (const float*)d_in[5];
  const float* b_idkv = (const float*)d_in[6];
  const float* w_proj = (const float*)d_in[7];
  const float* b_proj = (const float*)d_in[8];

  float* out     = (float*)d_out;
  float* out_kmm = out + (size_t)3072 * 768;
  float* out_vm  = out_kmm + (size_t)12 * 1024 * 64;

  char* cur = (char*)d_ws;
  auto sub = [&](size_t b) { char* p = cur; cur += (b + 255) & ~(size_t)255; return p; };

  // ---- union region: early temps (dead after split/build) vs av_part ----
  char* uni0 = cur;
  bf16*  x_bf     = (bf16*) sub((size_t)3072 * 768 * 2);
  bf16*  wqkv_bf  = (bf16*) sub((size_t)2304 * 768 * 2);
  bf16*  id_bf    = (bf16*) sub((size_t)1024 * 768 * 2);
  bf16*  widkv_bf = (bf16*) sub((size_t)780 * 768 * 2);
  float* qkv_f    = (float*)sub((size_t)3072 * 2304 * 4);
  float* idkv_f   = (float*)sub((size_t)1024 * 780 * 4);
  char* uniEndA = cur;
  float* av_part = (float*)uni0;                       // 4 * 3072*768 f32
  char* uniEndB = uni0 + (size_t)4 * 3072 * 768 * 4;
  cur = (uniEndA > uniEndB) ? uniEndA : uniEndB;

  // ---- persistent ----
  bf16*   wproj_bf = (bf16*)  sub((size_t)768 * 768 * 2);
  bf16*   q_bf     = (bf16*)  sub((size_t)12 * 3072 * 64 * 2);
  bf16*   kfull_bf = (bf16*)  sub((size_t)12 * 5120 * 64 * 2);
  bf16*   vT_bf    = (bf16*)  sub((size_t)12 * 64 * 5120 * 2);
  bf16*   kmm_bf   = (bf16*)  sub((size_t)12 * 1024 * 64 * 2);
  bf16*   S_m      = (bf16*)  sub((size_t)12 * 1024 * 1024 * 2);
  float4* stats_m  = (float4*)sub((size_t)12 * 1024 * 16);
  float4* stats_s  = (float4*)sub((size_t)12 * 2048 * 16);
  bf16*   xatt_bf  = (bf16*)  sub((size_t)3072 * 768 * 2);
  size_t fixed = (size_t)(cur - (char*)d_ws);

  int CH = 1;
  const int chs[6] = {12, 6, 4, 3, 2, 1};
  for (int i = 0; i < 6; ++i) {
    if (fixed + (size_t)chs[i] * 2048 * 5120 * 2 + 256 <= ws_size) { CH = chs[i]; break; }
  }
  if (fixed + (size_t)CH * 2048 * 5120 * 2 + 256 > ws_size) return;
  bf16* S_s = (bf16*)sub((size_t)CH * 2048 * 5120 * 2);

  // --- bf16 conversions ---
  to_bf16_k<<<2304, 256, 0, stream>>>((const float4*)x,      (bf16x4*)x_bf,     589824);
  to_bf16_k<<<1728, 256, 0, stream>>>((const float4*)w_qkv,  (bf16x4*)wqkv_bf,  442368);
  to_bf16_k<<< 768, 256, 0, stream>>>((const float4*)id_tot, (bf16x4*)id_bf,    196608);
  to_bf16_k<<< 585, 256, 0, stream>>>((const float4*)w_idkv, (bf16x4*)widkv_bf, 149760);
  to_bf16_k<<< 576, 256, 0, stream>>>((const float4*)w_proj, (bf16x4*)wproj_bf, 147456);

  // --- projections ---
  gemm_nt<128,128,64,64,false,false><<<dim3(18, 24, 1), 256, 0, stream>>>(
      x_bf, wqkv_bf, qkv_f, nullptr, 3072, 2304, 768, 768, 768, 2304, 0, 0, 0);
  gemm_nt<128,128,64,64,false,true><<<dim3(7, 8, 1), 256, 0, stream>>>(
      id_bf, widkv_bf, idkv_f, b_idkv, 1024, 780, 768, 768, 768, 780, 0, 0, 0);

  // --- split + modulate + transposes (consume qkv_f/idkv_f) ---
  split_qk_k<<<15360, 256, 0, stream>>>(qkv_f, idkv_f, mem_k, q_bf, kfull_bf, kmm_bf, out_kmm);
  build_vT_k<<<dim3(80, 12, 1), 256, 0, stream>>>(qkv_f, idkv_f, mem_v, vT_bf, out_vm);

  // --- memory-branch attention (L=1024) ---
  gemm_nt<128,128,64,64,true,false><<<dim3(8, 8, 12), 256, 0, stream>>>(
      q_bf, kmm_bf, S_m, nullptr, 1024, 1024, 64, 64, 64, 1024,
      (long)3072 * 64, (long)1024 * 64, (long)1024 * 1024);
  row_stats<1024><<<12288, 256, 0, stream>>>(S_m, stats_m);
  av_fused<2><<<dim3(16, 12, 2), 256, 0, stream>>>(
      S_m, stats_m, vT_bf, av_part, 1024, 1024, 2048, 0, 0);

  // --- streaming-branch attention (L=5120), chunked over heads ---
  for (int h0 = 0; h0 < 12; h0 += CH) {
    gemm_nt<128,128,64,64,true,false><<<dim3(40, 16, CH), 256, 0, stream>>>(
        q_bf + (size_t)h0 * 3072 * 64 + 1024 * 64, kfull_bf + (size_t)h0 * 5120 * 64,
        S_s, nullptr, 2048, 5120, 64, 64, 64, 5120,
        (long)3072 * 64, (long)5120 * 64, (long)2048 * 5120);
    row_stats<5120><<<CH * 2048, 256, 0, stream>>>(S_s, stats_s + (size_t)h0 * 2048);
    av_fused<4><<<dim3(32, CH, 4), 256, 0, stream>>>(
        S_s, stats_s, vT_bf, av_part, 2048, 5120, 0, 1024, h0);
  }

  // --- reduce partials + output projection ---
  reduce_cvt_k<<<2304, 256, 0, stream>>>((const float4*)av_part, (bf16x4*)xatt_bf);
  gemm_nt<128,128,64,64,false,false><<<dim3(6, 24, 1), 256, 0, stream>>>(
      xatt_bf, wproj_bf, out, b_proj, 3072, 768, 768, 768, 768, 768, 0, 0, 0);
}